// Round 6
// baseline (300.978 us; speedup 1.0000x reference)
//
#include <hip/hip_runtime.h>
#include <hip/hip_bf16.h>

using bf16 = __hip_bfloat16;
typedef short bf16x8 __attribute__((ext_vector_type(8)));
typedef float f32x4 __attribute__((ext_vector_type(4)));
typedef unsigned short ushort8_t __attribute__((ext_vector_type(8)));
typedef unsigned long long u64;

static constexpr int NA_ = 2048, NB_ = 2048;
static constexpr int H_ = 8, DH_ = 64, INNER_ = 512;
static constexpr int MROWS = 2 * NA_;  // 4096 rows for both batches
// LDS row stride for 64-col bf16 tiles: 76 bf16 = 38 dw == 6 (mod 32) ->
// frag-read bank pattern (6*lm + 4*quad) is ~2-way (free); 72 gave 8-way (2.9x).
static constexpr int KST = 76;

#define MFMA32(a, b, c) __builtin_amdgcn_mfma_f32_16x16x32_bf16(a, b, c, 0, 0, 0)

__device__ __forceinline__ unsigned short bfbits(float x) {
  bf16 h = __float2bfloat16(x);
  return __builtin_bit_cast(unsigned short, h);
}
__device__ __forceinline__ float b2f(unsigned short u) {
  unsigned v = ((unsigned)u) << 16;
  return __builtin_bit_cast(float, v);
}

// ======== prep: ln_feat (blocks 0..2047) | wconv (2048..4607) | maskpack (4608..6655)
__global__ __launch_bounds__(256) void prep_kernel(
    const float* __restrict__ fa_in, const float* __restrict__ fb_in,
    const float* __restrict__ law, const float* __restrict__ lab,
    const float* __restrict__ lbw, const float* __restrict__ lbb,
    bf16* __restrict__ fa, bf16* __restrict__ fb,
    const float* __restrict__ Wq, const float* __restrict__ Wk,
    const float* __restrict__ Wv, const float* __restrict__ Wg,
    const float* __restrict__ Wo,
    bf16* __restrict__ Wqt, bf16* __restrict__ Wkt,
    bf16* __restrict__ Wvt, bf16* __restrict__ Wgt,
    bf16* __restrict__ Woth, bf16* __restrict__ Wotl,
    const void* __restrict__ maskp, u64* __restrict__ mbits) {
  int blk = blockIdx.x;
  int t = threadIdx.x;
  if (blk < 2048) {
    // ---- LN of feats, one wave per row ----
    int row = blk * 4 + (t >> 6);
    int lane = t & 63;
    const float *src, *w, *bb;
    bf16* dst;
    int r;
    if (row < MROWS) { src = fa_in; w = law; bb = lab; dst = fa; r = row; }
    else             { src = fb_in; w = lbw; bb = lbb; dst = fb; r = row - MROWS; }
    float4 x = *(const float4*)(src + (size_t)r * 256 + lane * 4);
    float s  = (x.x + x.y) + (x.z + x.w);
    float s2 = (x.x * x.x + x.y * x.y) + (x.z * x.z + x.w * x.w);
#pragma unroll
    for (int m = 32; m >= 1; m >>= 1) { s += __shfl_xor(s, m); s2 += __shfl_xor(s2, m); }
    float mean = s * (1.0f / 256.0f);
    float var  = s2 * (1.0f / 256.0f) - mean * mean;
    float rstd = rsqrtf(var + 1e-5f);
    float4 wv = *(const float4*)(w + lane * 4);
    float4 bv = *(const float4*)(bb + lane * 4);
    ushort4 o;
    o.x = bfbits((x.x - mean) * rstd * wv.x + bv.x);
    o.y = bfbits((x.y - mean) * rstd * wv.y + bv.y);
    o.z = bfbits((x.z - mean) * rstd * wv.z + bv.z);
    o.w = bfbits((x.w - mean) * rstd * wv.w + bv.w);
    *(ushort4*)(dst + (size_t)r * 256 + lane * 4) = o;
  } else if (blk < 4608) {
    // ---- weight convert/transpose ----
    int z = (blk - 2048) >> 9;
    int idx = ((blk - 2048) & 511) * 256 + t;  // 0..131071
    if (z < 4) {
      const float* W = (z == 0) ? Wq : (z == 1) ? Wk : (z == 2) ? Wv : Wg;
      bf16* Wt = (z == 0) ? Wqt : (z == 1) ? Wkt : (z == 2) ? Wvt : Wgt;
      int kk = idx >> 9, n = idx & 511;
      Wt[n * 256 + kk] = __float2bfloat16(W[idx]);
    } else {
      int kk = idx >> 8, n = idx & 255;
      float w = Wo[idx];
      bf16 hi = __float2bfloat16(w);
      Woth[n * 512 + kk] = hi;
      Wotl[n * 512 + kk] = __float2bfloat16(w - __bfloat162float(hi));
    }
  } else {
    // ---- mask bit-pack with per-block dtype self-detect ----
    __shared__ unsigned shf[4];
    const unsigned char* mu = (const unsigned char*)maskp;
    bool nz = ((t & 3) != 0) && (mu[t] != 0);
    u64 bal = __ballot(nz);
    if ((t & 63) == 0) shf[t >> 6] = (bal != 0ull) ? 1u : 0u;
    __syncthreads();
    bool m8 = (shf[0] | shf[1] | shf[2] | shf[3]) != 0;  // nonzero off-4 byte => u8
    int lane = t & 63, wid = t >> 6;
    int lb = blk - 4608;
    for (size_t word = (size_t)lb * 4 + wid; word < 131072; word += 8192) {
      size_t e = word * 64 + lane;
      int v = m8 ? (int)mu[e] : ((const int*)maskp)[e];
      u64 b2 = __ballot(v != 0);
      if (lane == 0) mbits[word] = b2;
    }
  }
}

// ======== all four pre-GEMMs in one launch: grid dim3(256,1,4) ========
// z=0: q = LN(fa@Wq+bq)  z=1: k = LN(fb@Wk+bk)   (m-tile 16, full N=512 per block)
// z=2: g = fa@Wg+bg (bf16 [M][512])  z=3: v^T layout (m-tile 128, n-tile 64)
__global__ __launch_bounds__(256) void gemm4_kernel(
    const bf16* __restrict__ fa, const bf16* __restrict__ fb,
    const bf16* __restrict__ Wqt, const bf16* __restrict__ Wkt,
    const bf16* __restrict__ Wgt, const bf16* __restrict__ Wvt,
    const float* __restrict__ bq, const float* __restrict__ bk,
    const float* __restrict__ bg, const float* __restrict__ bv,
    const float* __restrict__ qlw, const float* __restrict__ qlb,
    const float* __restrict__ klw, const float* __restrict__ klb,
    bf16* __restrict__ qo, bf16* __restrict__ ko,
    bf16* __restrict__ gout, bf16* __restrict__ vout) {
  __shared__ __align__(16) char sm[29184];
  int z = blockIdx.z;
  int t = threadIdx.x, wave = t >> 6, lane = t & 63;
  int lm = lane & 15, quad = lane >> 4, q8 = quad * 8;

  if (z < 2) {
    // ---------- q/k GEMM with fused LayerNorm ----------
    bf16* As = (bf16*)sm;                       // [16][268] = 8576 B
    float* Pred = (float*)(sm + 16896);         // [16][8]
    float* MV   = (float*)(sm + 17408);         // [16][2]
    const bf16* A    = z ? fb : fa;
    const bf16* Wt   = z ? Wkt : Wqt;
    const float* bias = z ? bk : bq;
    const float* lw  = z ? klw : qlw;
    const float* lb  = z ? klb : qlb;
    bf16* out        = z ? ko : qo;
    int m0 = blockIdx.x * 16;
    // stage A 16x256 (stride 268 == 134 dw == 6 mod 32)
#pragma unroll
    for (int i = 0; i < 2; i++) {
      int id = t + 256 * i, r = id >> 5, cg = id & 31;
      *(ushort8_t*)(&As[r * 268 + cg * 8]) =
          *(const ushort8_t*)(A + (size_t)(m0 + r) * 256 + cg * 8);
    }
    __syncthreads();
    int n0w = wave * 128;
    f32x4 acc[8] = {};
    const bf16* wrow[8];
#pragma unroll
    for (int ni = 0; ni < 8; ni++) wrow[ni] = Wt + (size_t)(n0w + ni * 16 + lm) * 256;
#pragma unroll
    for (int ks = 0; ks < 8; ks++) {
      int k0 = ks * 32;
      bf16x8 af = *(const bf16x8*)(&As[lm * 268 + k0 + q8]);
#pragma unroll
      for (int ni = 0; ni < 8; ni++) {
        bf16x8 bf_ = *(const bf16x8*)(wrow[ni] + k0 + q8);
        acc[ni] = MFMA32(af, bf_, acc[ni]);
      }
    }
    float bvv[8];
#pragma unroll
    for (int ni = 0; ni < 8; ni++) bvv[ni] = bias[n0w + ni * 16 + lm];
#pragma unroll
    for (int ni = 0; ni < 8; ni++)
#pragma unroll
      for (int r = 0; r < 4; r++) acc[ni][r] += bvv[ni];
    // per-row stats over the wave's 128 cols
#pragma unroll
    for (int r = 0; r < 4; r++) {
      float s = 0.f, s2 = 0.f;
#pragma unroll
      for (int ni = 0; ni < 8; ni++) { s += acc[ni][r]; s2 += acc[ni][r] * acc[ni][r]; }
#pragma unroll
      for (int m = 1; m <= 8; m <<= 1) { s += __shfl_xor(s, m); s2 += __shfl_xor(s2, m); }
      if (lm == 0) {
        int row = quad * 4 + r;
        Pred[row * 8 + wave * 2]     = s;
        Pred[row * 8 + wave * 2 + 1] = s2;
      }
    }
    __syncthreads();
    if (t < 16) {
      float s = 0.f, s2 = 0.f;
#pragma unroll
      for (int w = 0; w < 4; w++) { s += Pred[t * 8 + w * 2]; s2 += Pred[t * 8 + w * 2 + 1]; }
      float mean = s * (1.0f / 512.0f);
      float var  = s2 * (1.0f / 512.0f) - mean * mean;
      MV[t * 2]     = mean;
      MV[t * 2 + 1] = rsqrtf(var + 1e-5f);
    }
    __syncthreads();
    float lww[8], lbb_[8];
#pragma unroll
    for (int ni = 0; ni < 8; ni++) {
      lww[ni]  = lw[n0w + ni * 16 + lm];
      lbb_[ni] = lb[n0w + ni * 16 + lm];
    }
#pragma unroll
    for (int r = 0; r < 4; r++) {
      int row = quad * 4 + r;
      float mean = MV[row * 2], rstd = MV[row * 2 + 1];
      size_t obase = (size_t)(m0 + row) * 512 + n0w;
#pragma unroll
      for (int ni = 0; ni < 8; ni++)
        out[obase + ni * 16 + lm] =
            __float2bfloat16((acc[ni][r] - mean) * rstd * lww[ni] + lbb_[ni]);
    }
  } else {
    // ---------- g/v GEMM: m-tile 128, n-tile 64 ----------
    bf16* As = (bf16*)sm;                    // [128][76] = 19456 B
    bf16* Bs = (bf16*)(sm + 19456);          // [64][76]  = 9728 B
    const bf16* A    = (z == 3) ? fb : fa;
    const bf16* Wt   = (z == 3) ? Wvt : Wgt;
    const float* bias = (z == 3) ? bv : bg;
    int x = blockIdx.x;
    int m0 = (x >> 3) * 128, n0 = (x & 7) * 64;
    int wm = wave * 32;
    f32x4 acc[2][4] = {};
    for (int k0 = 0; k0 < 256; k0 += 64) {
      __syncthreads();
#pragma unroll
      for (int i = 0; i < 4; i++) {
        int id = t + 256 * i, r = id >> 3, cg = id & 7;
        *(ushort8_t*)(&As[r * KST + cg * 8]) =
            *(const ushort8_t*)(A + (size_t)(m0 + r) * 256 + k0 + cg * 8);
      }
#pragma unroll
      for (int i = 0; i < 2; i++) {
        int id = t + 256 * i, r = id >> 3, cg = id & 7;
        *(ushort8_t*)(&Bs[r * KST + cg * 8]) =
            *(const ushort8_t*)(Wt + (size_t)(n0 + r) * 256 + k0 + cg * 8);
      }
      __syncthreads();
#pragma unroll
      for (int kk = 0; kk < 64; kk += 32) {
        bf16x8 af[2], bf_[4];
#pragma unroll
        for (int mi = 0; mi < 2; mi++)
          af[mi] = *(const bf16x8*)(&As[(wm + mi * 16 + lm) * KST + kk + q8]);
#pragma unroll
        for (int ni = 0; ni < 4; ni++)
          bf_[ni] = *(const bf16x8*)(&Bs[(ni * 16 + lm) * KST + kk + q8]);
#pragma unroll
        for (int mi = 0; mi < 2; mi++)
#pragma unroll
          for (int ni = 0; ni < 4; ni++)
            acc[mi][ni] = MFMA32(af[mi], bf_[ni], acc[mi][ni]);
      }
    }
    if (z == 2) {
#pragma unroll
      for (int mi = 0; mi < 2; mi++)
#pragma unroll
        for (int ni = 0; ni < 4; ni++) {
          int nn = n0 + ni * 16 + lm;
          float bvv = bias[nn];
          int mb = m0 + wm + mi * 16 + quad * 4;
#pragma unroll
          for (int r = 0; r < 4; r++)
            gout[(size_t)(mb + r) * 512 + nn] = __float2bfloat16(acc[mi][ni][r] + bvv);
        }
    } else {
      // v^T: bounce through LDS [64 d][136] for coalesced [d][j] write
      __syncthreads();
      bf16* buf = (bf16*)sm;
#pragma unroll
      for (int mi = 0; mi < 2; mi++)
#pragma unroll
        for (int ni = 0; ni < 4; ni++) {
          int d_local = ni * 16 + lm;
          float bvv = bias[n0 + d_local];
          int j_local = wm + mi * 16 + quad * 4;
#pragma unroll
          for (int r = 0; r < 4; r++)
            buf[d_local * 136 + j_local + r] = __float2bfloat16(acc[mi][ni][r] + bvv);
        }
      __syncthreads();
      int bidx2 = m0 >> 11, j0g = m0 & 2047, hh = n0 >> 6;
      int dl = t >> 2, jseg = (t & 3) * 32;
      bf16* dstrow = vout + (size_t)((bidx2 * 8 + hh) * 64 + dl) * 2048 + j0g + jseg;
#pragma unroll
      for (int c = 0; c < 4; c++)
        *(ushort8_t*)(dstrow + c * 8) = *(const ushort8_t*)(&buf[dl * 136 + jseg + c * 8]);
    }
  }
}

// ---------------- flash attention (R3 structure): fixed-max softmax, transposed-S ----
// 8 waves: waves 0-3 j in [0,1024), waves 4-7 j in [1024,2048); same 64 q-rows.
// St = K.Q^T -> lane holds q-row i = lane&15, j = nt*16 + quad*4 + r (regs).
// p = exp2(s*scale2); masked-dead zeroed AFTER exp. No max reduction, no alpha.
// LDS: K/V at stride 76 (2-way banks); P at 72; Q overlays P region (regs-resident).
__global__ __launch_bounds__(512) void attn_kernel(
    const bf16* __restrict__ q, const bf16* __restrict__ k,
    const bf16* __restrict__ vt, const bf16* __restrict__ g,
    const u64* __restrict__ mbits,
    bf16* __restrict__ gh, bf16* __restrict__ gl) {
  __shared__ __align__(16) char smem[57856];
  bf16* KsB = (bf16*)smem;                   // 2 * 64*76*2 = 19456 B
  bf16* VsB = (bf16*)(smem + 19456);         // 19456 B
  bf16* PsB = (bf16*)(smem + 38912);         // 8 * 16*72*2 = 18432 B
  bf16* Qs  = (bf16*)(smem + 38912);         // overlay on Ps: 64*76*2 = 9728 B
  float* Om = (float*)smem;                  // overlay on Ks: 4*16*66*4 = 16896 B
  float* Lbuf = (float*)(smem + 57344);      // 2*64 floats = 512 B

  int qt = blockIdx.x, bh = blockIdx.y;
  int bidx = bh >> 3, h = bh & 7;
  int i0 = qt * 64;
  int t = threadIdx.x, wave = t >> 6, lane = t & 63;
  int jhalf = wave >> 2, w4 = wave & 3;
  int lm = lane & 15, quad = lane >> 4, q8 = quad * 8;
  int lt = t & 255;

  // stage Q tile (64 rows x 64 dh), 512 threads x 16B = one shot
  {
    int r = t >> 3, cg = t & 7;
    *(ushort8_t*)(&Qs[r * KST + cg * 8]) =
        *(const ushort8_t*)(q + (size_t)(bidx * NA_ + i0 + r) * INNER_ + h * DH_ + cg * 8);
  }
  __syncthreads();
  bf16x8 bq0 = *(const bf16x8*)(&Qs[(w4 * 16 + lm) * KST + q8]);
  bf16x8 bq1 = *(const bf16x8*)(&Qs[(w4 * 16 + lm) * KST + 32 + q8]);

  f32x4 oacc[4] = {};
  float psum = 0.f;
  const float scale2 = 0.125f * 1.44269504088896f;

  const bf16* kb = k + (size_t)(bidx * NB_) * INNER_ + h * DH_;
  const bf16* vb = vt + (size_t)(bh * DH_) * NB_;
  bf16* Pw = PsB + wave * (16 * 72);
  bf16* Ks = KsB + jhalf * (64 * KST);
  bf16* Vs = VsB + jhalf * (64 * KST);
  const u64* mrp = mbits + ((size_t)(bidx * NA_ + i0 + w4 * 16 + lm)) * (NB_ / 64) + jhalf * 16;

  for (int it = 0; it < 16; it++) {
    int j0 = jhalf * 1024 + it * 64;
    __syncthreads();
#pragma unroll
    for (int i = 0; i < 2; i++) {
      int id = lt + 256 * i, r = id >> 3, cg = id & 7;
      *(ushort8_t*)(&Ks[r * KST + cg * 8]) =
          *(const ushort8_t*)(kb + (size_t)(j0 + r) * INNER_ + cg * 8);
      *(ushort8_t*)(&Vs[r * KST + cg * 8]) =
          *(const ushort8_t*)(vb + (size_t)r * NB_ + j0 + cg * 8);
    }
    u64 sm = mrp[it] >> (quad * 4);
    __syncthreads();

    // St = K.Q^T : 4 j-subtiles of 16
    f32x4 st[4];
#pragma unroll
    for (int nt = 0; nt < 4; nt++) {
      bf16x8 a0 = *(const bf16x8*)(&Ks[(nt * 16 + lm) * KST + q8]);
      bf16x8 a1 = *(const bf16x8*)(&Ks[(nt * 16 + lm) * KST + 32 + q8]);
      f32x4 a = {0.f, 0.f, 0.f, 0.f};
      a = MFMA32(a0, bq0, a);
      a = MFMA32(a1, bq1, a);
      st[nt] = a;
    }

    // p = exp2(s*scale2), zero dead via bit
    float pr[4][4];
#pragma unroll
    for (int nt = 0; nt < 4; nt++)
#pragma unroll
      for (int r = 0; r < 4; r++) {
        float p = exp2f(st[nt][r] * scale2);
        unsigned live = (unsigned)(sm >> (nt * 16 + r)) & 1u;
        pr[nt][r] = live ? p : 0.0f;
      }

    float s0 = (pr[0][0] + pr[0][1]) + (pr[0][2] + pr[0][3]);
    float s1 = (pr[1][0] + pr[1][1]) + (pr[1][2] + pr[1][3]);
    float s2 = (pr[2][0] + pr[2][1]) + (pr[2][2] + pr[2][3]);
    float s3 = (pr[3][0] + pr[3][1]) + (pr[3][2] + pr[3][3]);
    psum += (s0 + s1) + (s2 + s3);

    // P store: row i = lm, j = nt*16 + quad*4 + r (b64 writes, same-wave)
#pragma unroll
    for (int nt = 0; nt < 4; nt++) {
      ushort4 pk;
      pk.x = bfbits(pr[nt][0]);
      pk.y = bfbits(pr[nt][1]);
      pk.z = bfbits(pr[nt][2]);
      pk.w = bfbits(pr[nt][3]);
      *(ushort4*)(Pw + lm * 72 + nt * 16 + quad * 4) = pk;
    }

    // PV: A = P [m=i][k=j], B = V^T [n=d][k=j] -> O[i][d]
    bf16x8 ap0 = *(const bf16x8*)(&Pw[lm * 72 + q8]);
    bf16x8 ap1 = *(const bf16x8*)(&Pw[lm * 72 + 32 + q8]);
#pragma unroll
    for (int c = 0; c < 4; c++) {
      bf16x8 v0 = *(const bf16x8*)(&Vs[(c * 16 + lm) * KST + q8]);
      bf16x8 v1 = *(const bf16x8*)(&Vs[(c * 16 + lm) * KST + 32 + q8]);
      oacc[c] = MFMA32(ap0, v0, oacc[c]);
      oacc[c] = MFMA32(ap1, v1, oacc[c]);
    }
  }

  // row sums across quads (row i = lm)
  psum += __shfl_xor(psum, 16);
  psum += __shfl_xor(psum, 32);

  // -------- intra-block merge of the two j-halves --------
  __syncthreads();
  if (quad == 0) Lbuf[jhalf * 64 + w4 * 16 + lm] = psum;
  if (jhalf == 1) {
#pragma unroll
    for (int c = 0; c < 4; c++)
#pragma unroll
      for (int r = 0; r < 4; r++)
        Om[w4 * (16 * 66) + (quad * 4 + r) * 66 + c * 16 + lm] = oacc[c][r];
  }
  __syncthreads();
  if (jhalf == 0) {
    int mrow = i0 + w4 * 16 + quad * 4;
    float inv[4];
#pragma unroll
    for (int r = 0; r < 4; r++) {
      float l = Lbuf[w4 * 16 + quad * 4 + r] + Lbuf[64 + w4 * 16 + quad * 4 + r];
      inv[r] = 1.0f / l;
    }
#pragma unroll
    for (int c = 0; c < 4; c++) {
      int col = h * DH_ + c * 16 + lm;
#pragma unroll
      for (int r = 0; r < 4; r++) {
        float o = oacc[c][r] + Om[w4 * (16 * 66) + (quad * 4 + r) * 66 + c * 16 + lm];
        size_t idx = (size_t)(bidx * NA_ + mrow + r) * INNER_ + col;
        float gv = b2f(__builtin_bit_cast(unsigned short, g[idx]));
        float sig = 1.0f / (1.0f + __expf(-gv));
        float val = o * inv[r] * sig;
        unsigned short hb = bfbits(val);
        gh[idx] = __builtin_bit_cast(bf16, hb);
        gl[idx] = __float2bfloat16(val - b2f(hb));
      }
    }
  }
}

// ---------------- final GEMM in split-bf16 (hi/lo), 32x64 tiles, fp32 out -------
__global__ __launch_bounds__(256) void gemm_split_kernel(
    const bf16* __restrict__ Ah, const bf16* __restrict__ Al,
    const bf16* __restrict__ Bh, const bf16* __restrict__ Bl,
    const float* __restrict__ bias, float* __restrict__ C) {
  constexpr int K = 512, N = 256;
  __shared__ __align__(16) bf16 Ash[32 * KST];
  __shared__ __align__(16) bf16 Asl[32 * KST];
  __shared__ __align__(16) bf16 Bsh[64 * KST];
  __shared__ __align__(16) bf16 Bsl[64 * KST];
  int n0 = blockIdx.x * 64, m0 = blockIdx.y * 32;
  int t = threadIdx.x, wave = t >> 6, lane = t & 63;
  int lm = lane & 15, quad = lane >> 4, q8 = quad * 8;
  int wm = (wave & 1) * 16, wn = (wave >> 1) * 32;
  f32x4 acc[2] = {};
  for (int k0 = 0; k0 < K; k0 += 64) {
    __syncthreads();
    {
      int r = t >> 3, cg = t & 7;
      size_t ga = (size_t)(m0 + r) * K + k0 + cg * 8;
      *(ushort8_t*)(&Ash[r * KST + cg * 8]) = *(const ushort8_t*)(Ah + ga);
      *(ushort8_t*)(&Asl[r * KST + cg * 8]) = *(const ushort8_t*)(Al + ga);
    }
#pragma unroll
    for (int i = 0; i < 2; i++) {
      int id = t + 256 * i, r = id >> 3, cg = id & 7;
      size_t gb = (size_t)(n0 + r) * K + k0 + cg * 8;
      *(ushort8_t*)(&Bsh[r * KST + cg * 8]) = *(const ushort8_t*)(Bh + gb);
      *(ushort8_t*)(&Bsl[r * KST + cg * 8]) = *(const ushort8_t*)(Bl + gb);
    }
    __syncthreads();
#pragma unroll
    for (int kk = 0; kk < 64; kk += 32) {
      bf16x8 ah = *(const bf16x8*)(&Ash[(wm + lm) * KST + kk + q8]);
      bf16x8 al = *(const bf16x8*)(&Asl[(wm + lm) * KST + kk + q8]);
#pragma unroll
      for (int ni = 0; ni < 2; ni++) {
        bf16x8 bh_ = *(const bf16x8*)(&Bsh[(wn + ni * 16 + lm) * KST + kk + q8]);
        bf16x8 bl_ = *(const bf16x8*)(&Bsl[(wn + ni * 16 + lm) * KST + kk + q8]);
        acc[ni] = MFMA32(ah, bh_, acc[ni]);
        acc[ni] = MFMA32(ah, bl_, acc[ni]);
        acc[ni] = MFMA32(al, bh_, acc[ni]);
      }
    }
  }
#pragma unroll
  for (int ni = 0; ni < 2; ni++) {
    int n = n0 + wn + ni * 16 + lm;
    float bvv = bias[n];
    int mb = m0 + wm + quad * 4;
#pragma unroll
    for (int r = 0; r < 4; r++) C[(size_t)(mb + r) * N + n] = acc[ni][r] + bvv;
  }
}

extern "C" void kernel_launch(void* const* d_in, const int* in_sizes, int n_in,
                              void* d_out, int out_size, void* d_ws, size_t ws_size,
                              hipStream_t stream) {
  const float* feat_a = (const float*)d_in[0];
  const float* feat_b = (const float*)d_in[1];
  const void*  mask   = d_in[2];
  const float* Wq = (const float*)d_in[3];
  const float* bq = (const float*)d_in[4];
  const float* Wk = (const float*)d_in[5];
  const float* bk = (const float*)d_in[6];
  const float* Wv = (const float*)d_in[7];
  const float* bv = (const float*)d_in[8];
  const float* Wg = (const float*)d_in[9];
  const float* bg = (const float*)d_in[10];
  const float* Wo = (const float*)d_in[11];
  const float* bo = (const float*)d_in[12];
  const float* law = (const float*)d_in[13];
  const float* lab = (const float*)d_in[14];
  const float* lbw = (const float*)d_in[15];
  const float* lbb = (const float*)d_in[16];
  const float* qlw = (const float*)d_in[17];
  const float* qlb = (const float*)d_in[18];
  const float* klw = (const float*)d_in[19];
  const float* klb = (const float*)d_in[20];

  char* ws = (char*)d_ws;
  size_t off = 0;
  auto alloc = [&](size_t bytes) -> void* {
    void* p = ws + off;
    off += (bytes + 255) & ~(size_t)255;
    return p;
  };
  bf16* fa    = (bf16*)alloc((size_t)MROWS * 256 * 2);
  bf16* fb    = (bf16*)alloc((size_t)MROWS * 256 * 2);
  bf16* Wqt   = (bf16*)alloc((size_t)131072 * 2);
  bf16* Wkt   = (bf16*)alloc((size_t)131072 * 2);
  bf16* Wvt   = (bf16*)alloc((size_t)131072 * 2);
  bf16* Wgt   = (bf16*)alloc((size_t)131072 * 2);
  bf16* Woth  = (bf16*)alloc((size_t)131072 * 2);
  bf16* Wotl  = (bf16*)alloc((size_t)131072 * 2);
  bf16* qb_   = (bf16*)alloc((size_t)MROWS * 512 * 2);
  bf16* kb_   = (bf16*)alloc((size_t)MROWS * 512 * 2);
  bf16* vtb   = (bf16*)alloc((size_t)1024 * 2048 * 2);
  bf16* gbuf  = (bf16*)alloc((size_t)MROWS * 512 * 2);
  bf16* gh    = (bf16*)alloc((size_t)MROWS * 512 * 2);
  bf16* gl    = (bf16*)alloc((size_t)MROWS * 512 * 2);
  u64*  mbits = (u64*)alloc((size_t)131072 * 8);

  prep_kernel<<<6656, 256, 0, stream>>>(
      feat_a, feat_b, law, lab, lbw, lbb, fa, fb,
      Wq, Wk, Wv, Wg, Wo, Wqt, Wkt, Wvt, Wgt, Woth, Wotl, mask, mbits);
  gemm4_kernel<<<dim3(256, 1, 4), 256, 0, stream>>>(
      fa, fb, Wqt, Wkt, Wgt, Wvt, bq, bk, bg, bv,
      qlw, qlb, klw, klb, qb_, kb_, gbuf, vtb);
  attn_kernel<<<dim3(32, 16), 512, 0, stream>>>(qb_, kb_, vtb, gbuf, mbits, gh, gl);
  gemm_split_kernel<<<dim3(4, 128), 256, 0, stream>>>(gh, gl, Woth, Wotl, bo, (float*)d_out);
}

// Round 7
// 203.797 us; speedup vs baseline: 1.4769x; 1.4769x over previous
//
#include <hip/hip_runtime.h>
#include <hip/hip_bf16.h>

using bf16 = __hip_bfloat16;
typedef short bf16x8 __attribute__((ext_vector_type(8)));
typedef float f32x4 __attribute__((ext_vector_type(4)));
typedef unsigned short ushort8_t __attribute__((ext_vector_type(8)));
typedef unsigned long long u64;

static constexpr int NA_ = 2048, NB_ = 2048;
static constexpr int H_ = 8, DH_ = 64, INNER_ = 512;
static constexpr int MROWS = 2 * NA_;  // 4096 rows for both batches

#define MFMA32(a, b, c) __builtin_amdgcn_mfma_f32_16x16x32_bf16(a, b, c, 0, 0, 0)

__device__ __forceinline__ unsigned short bfbits(float x) {
  bf16 h = __float2bfloat16(x);
  return __builtin_bit_cast(unsigned short, h);
}
__device__ __forceinline__ float b2f(unsigned short u) {
  unsigned v = ((unsigned)u) << 16;
  return __builtin_bit_cast(float, v);
}

// ======== prep: ln_feat (blocks 0..2047) | wconv (2048..4607) | maskpack (4608..6655)
__global__ __launch_bounds__(256) void prep_kernel(
    const float* __restrict__ fa_in, const float* __restrict__ fb_in,
    const float* __restrict__ law, const float* __restrict__ lab,
    const float* __restrict__ lbw, const float* __restrict__ lbb,
    bf16* __restrict__ fa, bf16* __restrict__ fb,
    const float* __restrict__ Wq, const float* __restrict__ Wk,
    const float* __restrict__ Wv, const float* __restrict__ Wg,
    const float* __restrict__ Wo,
    bf16* __restrict__ Wqt, bf16* __restrict__ Wkt,
    bf16* __restrict__ Wvt, bf16* __restrict__ Wgt,
    bf16* __restrict__ Woth, bf16* __restrict__ Wotl,
    const void* __restrict__ maskp, u64* __restrict__ mbits) {
  int blk = blockIdx.x;
  int t = threadIdx.x;
  if (blk < 2048) {
    // ---- LN of feats, one wave per row ----
    int row = blk * 4 + (t >> 6);
    int lane = t & 63;
    const float *src, *w, *bb;
    bf16* dst;
    int r;
    if (row < MROWS) { src = fa_in; w = law; bb = lab; dst = fa; r = row; }
    else             { src = fb_in; w = lbw; bb = lbb; dst = fb; r = row - MROWS; }
    float4 x = *(const float4*)(src + (size_t)r * 256 + lane * 4);
    float s  = (x.x + x.y) + (x.z + x.w);
    float s2 = (x.x * x.x + x.y * x.y) + (x.z * x.z + x.w * x.w);
#pragma unroll
    for (int m = 32; m >= 1; m >>= 1) { s += __shfl_xor(s, m); s2 += __shfl_xor(s2, m); }
    float mean = s * (1.0f / 256.0f);
    float var  = s2 * (1.0f / 256.0f) - mean * mean;
    float rstd = rsqrtf(var + 1e-5f);
    float4 wv = *(const float4*)(w + lane * 4);
    float4 bv = *(const float4*)(bb + lane * 4);
    ushort4 o;
    o.x = bfbits((x.x - mean) * rstd * wv.x + bv.x);
    o.y = bfbits((x.y - mean) * rstd * wv.y + bv.y);
    o.z = bfbits((x.z - mean) * rstd * wv.z + bv.z);
    o.w = bfbits((x.w - mean) * rstd * wv.w + bv.w);
    *(ushort4*)(dst + (size_t)r * 256 + lane * 4) = o;
  } else if (blk < 4608) {
    // ---- weight convert/transpose ----
    int z = (blk - 2048) >> 9;
    int idx = ((blk - 2048) & 511) * 256 + t;  // 0..131071
    if (z < 4) {
      const float* W = (z == 0) ? Wq : (z == 1) ? Wk : (z == 2) ? Wv : Wg;
      bf16* Wt = (z == 0) ? Wqt : (z == 1) ? Wkt : (z == 2) ? Wvt : Wgt;
      int kk = idx >> 9, n = idx & 511;
      Wt[n * 256 + kk] = __float2bfloat16(W[idx]);
    } else {
      int kk = idx >> 8, n = idx & 255;
      float w = Wo[idx];
      bf16 hi = __float2bfloat16(w);
      Woth[n * 512 + kk] = hi;
      Wotl[n * 512 + kk] = __float2bfloat16(w - __bfloat162float(hi));
    }
  } else {
    // ---- mask bit-pack with per-block dtype self-detect ----
    __shared__ unsigned shf[4];
    const unsigned char* mu = (const unsigned char*)maskp;
    bool nz = ((t & 3) != 0) && (mu[t] != 0);
    u64 bal = __ballot(nz);
    if ((t & 63) == 0) shf[t >> 6] = (bal != 0ull) ? 1u : 0u;
    __syncthreads();
    bool m8 = (shf[0] | shf[1] | shf[2] | shf[3]) != 0;  // nonzero off-4 byte => u8
    int lane = t & 63, wid = t >> 6;
    int lb = blk - 4608;
    for (size_t word = (size_t)lb * 4 + wid; word < 131072; word += 8192) {
      size_t e = word * 64 + lane;
      int v = m8 ? (int)mu[e] : ((const int*)maskp)[e];
      u64 b2 = __ballot(v != 0);
      if (lane == 0) mbits[word] = b2;
    }
  }
}

// ======== all four pre-GEMMs in one launch: grid dim3(256,1,4) ========
// z=0: q = LN(fa@Wq+bq)  z=1: k = LN(fb@Wk+bk)   (m-tile 16, full N=512 per block)
// z=2: g = fa@Wg+bg (bf16 [M][512])  z=3: v^T layout (m-tile 128, n-tile 64)
__global__ __launch_bounds__(256) void gemm4_kernel(
    const bf16* __restrict__ fa, const bf16* __restrict__ fb,
    const bf16* __restrict__ Wqt, const bf16* __restrict__ Wkt,
    const bf16* __restrict__ Wgt, const bf16* __restrict__ Wvt,
    const float* __restrict__ bq, const float* __restrict__ bk,
    const float* __restrict__ bg, const float* __restrict__ bv,
    const float* __restrict__ qlw, const float* __restrict__ qlb,
    const float* __restrict__ klw, const float* __restrict__ klb,
    bf16* __restrict__ qo, bf16* __restrict__ ko,
    bf16* __restrict__ gout, bf16* __restrict__ vout) {
  __shared__ __align__(16) char sm[27648];
  int z = blockIdx.z;
  int t = threadIdx.x, wave = t >> 6, lane = t & 63;
  int lm = lane & 15, quad = lane >> 4, q8 = quad * 8;

  if (z < 2) {
    // ---------- q/k GEMM with fused LayerNorm ----------
    bf16* As = (bf16*)sm;                       // [16][264] = 8448 B
    float* Pred = (float*)(sm + 16896);         // [16][8]
    float* MV   = (float*)(sm + 17408);         // [16][2]
    const bf16* A    = z ? fb : fa;
    const bf16* Wt   = z ? Wkt : Wqt;
    const float* bias = z ? bk : bq;
    const float* lw  = z ? klw : qlw;
    const float* lb  = z ? klb : qlb;
    bf16* out        = z ? ko : qo;
    int m0 = blockIdx.x * 16;
    // stage A 16x256 (stride 264 B-aligned 16)
#pragma unroll
    for (int i = 0; i < 2; i++) {
      int id = t + 256 * i, r = id >> 5, cg = id & 31;
      *(ushort8_t*)(&As[r * 264 + cg * 8]) =
          *(const ushort8_t*)(A + (size_t)(m0 + r) * 256 + cg * 8);
    }
    __syncthreads();
    int n0w = wave * 128;
    f32x4 acc[8] = {};
    const bf16* wrow[8];
#pragma unroll
    for (int ni = 0; ni < 8; ni++) wrow[ni] = Wt + (size_t)(n0w + ni * 16 + lm) * 256;
#pragma unroll
    for (int ks = 0; ks < 8; ks++) {
      int k0 = ks * 32;
      bf16x8 af = *(const bf16x8*)(&As[lm * 264 + k0 + q8]);
#pragma unroll
      for (int ni = 0; ni < 8; ni++) {
        bf16x8 bf_ = *(const bf16x8*)(wrow[ni] + k0 + q8);
        acc[ni] = MFMA32(af, bf_, acc[ni]);
      }
    }
    float bvv[8];
#pragma unroll
    for (int ni = 0; ni < 8; ni++) bvv[ni] = bias[n0w + ni * 16 + lm];
#pragma unroll
    for (int ni = 0; ni < 8; ni++)
#pragma unroll
      for (int r = 0; r < 4; r++) acc[ni][r] += bvv[ni];
    // per-row stats over the wave's 128 cols
#pragma unroll
    for (int r = 0; r < 4; r++) {
      float s = 0.f, s2 = 0.f;
#pragma unroll
      for (int ni = 0; ni < 8; ni++) { s += acc[ni][r]; s2 += acc[ni][r] * acc[ni][r]; }
#pragma unroll
      for (int m = 1; m <= 8; m <<= 1) { s += __shfl_xor(s, m); s2 += __shfl_xor(s2, m); }
      if (lm == 0) {
        int row = quad * 4 + r;
        Pred[row * 8 + wave * 2]     = s;
        Pred[row * 8 + wave * 2 + 1] = s2;
      }
    }
    __syncthreads();
    if (t < 16) {
      float s = 0.f, s2 = 0.f;
#pragma unroll
      for (int w = 0; w < 4; w++) { s += Pred[t * 8 + w * 2]; s2 += Pred[t * 8 + w * 2 + 1]; }
      float mean = s * (1.0f / 512.0f);
      float var  = s2 * (1.0f / 512.0f) - mean * mean;
      MV[t * 2]     = mean;
      MV[t * 2 + 1] = rsqrtf(var + 1e-5f);
    }
    __syncthreads();
    float lww[8], lbb_[8];
#pragma unroll
    for (int ni = 0; ni < 8; ni++) {
      lww[ni]  = lw[n0w + ni * 16 + lm];
      lbb_[ni] = lb[n0w + ni * 16 + lm];
    }
#pragma unroll
    for (int r = 0; r < 4; r++) {
      int row = quad * 4 + r;
      float mean = MV[row * 2], rstd = MV[row * 2 + 1];
      size_t obase = (size_t)(m0 + row) * 512 + n0w;
#pragma unroll
      for (int ni = 0; ni < 8; ni++)
        out[obase + ni * 16 + lm] =
            __float2bfloat16((acc[ni][r] - mean) * rstd * lww[ni] + lbb_[ni]);
    }
  } else {
    // ---------- g/v GEMM: m-tile 128, n-tile 64 (stride 72, 16-B aligned) ----------
    bf16* As = (bf16*)sm;                 // [128][72] = 18432 B
    bf16* Bs = (bf16*)(sm + 18432);       // [64][72]  = 9216 B
    const bf16* A    = (z == 3) ? fb : fa;
    const bf16* Wt   = (z == 3) ? Wvt : Wgt;
    const float* bias = (z == 3) ? bv : bg;
    int x = blockIdx.x;
    int m0 = (x >> 3) * 128, n0 = (x & 7) * 64;
    int wm = wave * 32;
    f32x4 acc[2][4] = {};
    for (int k0 = 0; k0 < 256; k0 += 64) {
      __syncthreads();
#pragma unroll
      for (int i = 0; i < 4; i++) {
        int id = t + 256 * i, r = id >> 3, cg = id & 7;
        *(ushort8_t*)(&As[r * 72 + cg * 8]) =
            *(const ushort8_t*)(A + (size_t)(m0 + r) * 256 + k0 + cg * 8);
      }
#pragma unroll
      for (int i = 0; i < 2; i++) {
        int id = t + 256 * i, r = id >> 3, cg = id & 7;
        *(ushort8_t*)(&Bs[r * 72 + cg * 8]) =
            *(const ushort8_t*)(Wt + (size_t)(n0 + r) * 256 + k0 + cg * 8);
      }
      __syncthreads();
#pragma unroll
      for (int kk = 0; kk < 64; kk += 32) {
        bf16x8 af[2], bf_[4];
#pragma unroll
        for (int mi = 0; mi < 2; mi++)
          af[mi] = *(const bf16x8*)(&As[(wm + mi * 16 + lm) * 72 + kk + q8]);
#pragma unroll
        for (int ni = 0; ni < 4; ni++)
          bf_[ni] = *(const bf16x8*)(&Bs[(ni * 16 + lm) * 72 + kk + q8]);
#pragma unroll
        for (int mi = 0; mi < 2; mi++)
#pragma unroll
          for (int ni = 0; ni < 4; ni++)
            acc[mi][ni] = MFMA32(af[mi], bf_[ni], acc[mi][ni]);
      }
    }
    if (z == 2) {
#pragma unroll
      for (int mi = 0; mi < 2; mi++)
#pragma unroll
        for (int ni = 0; ni < 4; ni++) {
          int nn = n0 + ni * 16 + lm;
          float bvv = bias[nn];
          int mb = m0 + wm + mi * 16 + quad * 4;
#pragma unroll
          for (int r = 0; r < 4; r++)
            gout[(size_t)(mb + r) * 512 + nn] = __float2bfloat16(acc[mi][ni][r] + bvv);
        }
    } else {
      // v^T: bounce through LDS [64 d][136] for coalesced [d][j] write
      __syncthreads();
      bf16* buf = (bf16*)sm;
#pragma unroll
      for (int mi = 0; mi < 2; mi++)
#pragma unroll
        for (int ni = 0; ni < 4; ni++) {
          int d_local = ni * 16 + lm;
          float bvv = bias[n0 + d_local];
          int j_local = wm + mi * 16 + quad * 4;
#pragma unroll
          for (int r = 0; r < 4; r++)
            buf[d_local * 136 + j_local + r] = __float2bfloat16(acc[mi][ni][r] + bvv);
        }
      __syncthreads();
      int bidx2 = m0 >> 11, j0g = m0 & 2047, hh = n0 >> 6;
      int dl = t >> 2, jseg = (t & 3) * 32;
      bf16* dstrow = vout + (size_t)((bidx2 * 8 + hh) * 64 + dl) * 2048 + j0g + jseg;
#pragma unroll
      for (int c = 0; c < 4; c++)
        *(ushort8_t*)(dstrow + c * 8) = *(const ushort8_t*)(&buf[dl * 136 + jseg + c * 8]);
    }
  }
}

// ---------------- flash attention (R5 layout + register-double-buffered staging) ----
// 8 waves: waves 0-3 j in [0,1024), waves 4-7 j in [1024,2048); same 64 q-rows.
// St = K.Q^T -> lane holds q-row i = lane&15, j = nt*16 + quad*4 + r (regs).
// p = exp2(s*scale2); masked-dead zeroed AFTER exp. No max reduction, no alpha.
// K/V for tile it+1 loaded into REGISTERS during tile it's compute (overlaps
// global latency with MFMA/softmax instead of exposing it between barriers).
__global__ __launch_bounds__(512) void attn_kernel(
    const bf16* __restrict__ q, const bf16* __restrict__ k,
    const bf16* __restrict__ vt, const bf16* __restrict__ g,
    const u64* __restrict__ mbits,
    bf16* __restrict__ gh, bf16* __restrict__ gl) {
  __shared__ __align__(16) char smem[65024];
  bf16* Qs = (bf16*)smem;                    // 64*72 bf16 = 9216 B
  bf16* KsB = (bf16*)(smem + 9216);          // 2 * 9216 B
  bf16* VsB = (bf16*)(smem + 27648);         // 2 * 9216 B
  bf16* PsB = (bf16*)(smem + 46080);         // 8 * 16*72*2 = 18432 B
  float* Om = (float*)(smem + 9216);         // overlay on Ks: 4*16*66*4 = 16896 B
  float* Lbuf = (float*)(smem + 64512);      // 2*64 floats = 512 B

  int qt = blockIdx.x, bh = blockIdx.y;
  int bidx = bh >> 3, h = bh & 7;
  int i0 = qt * 64;
  int t = threadIdx.x, wave = t >> 6, lane = t & 63;
  int jhalf = wave >> 2, w4 = wave & 3;
  int lm = lane & 15, quad = lane >> 4, q8 = quad * 8;
  int lt = t & 255;
  int sr0 = lt >> 3, scg = (lt & 7) * 8;     // staging row/col for this thread

  // stage Q tile (64 rows x 64 dh), 512 threads x 16B = one shot
  {
    int r = t >> 3, cg = t & 7;
    *(ushort8_t*)(&Qs[r * 72 + cg * 8]) =
        *(const ushort8_t*)(q + (size_t)(bidx * NA_ + i0 + r) * INNER_ + h * DH_ + cg * 8);
  }
  __syncthreads();
  bf16x8 bq0 = *(const bf16x8*)(&Qs[(w4 * 16 + lm) * 72 + q8]);
  bf16x8 bq1 = *(const bf16x8*)(&Qs[(w4 * 16 + lm) * 72 + 32 + q8]);

  f32x4 oacc[4] = {};
  float psum = 0.f;
  const float scale2 = 0.125f * 1.44269504088896f;

  const bf16* kb = k + (size_t)(bidx * NB_) * INNER_ + h * DH_;
  const bf16* vb = vt + (size_t)(bh * DH_) * NB_;
  bf16* Pw = PsB + wave * (16 * 72);
  bf16* Ks = KsB + jhalf * (64 * 72);
  bf16* Vs = VsB + jhalf * (64 * 72);
  const u64* mrp = mbits + ((size_t)(bidx * NA_ + i0 + w4 * 16 + lm)) * (NB_ / 64) + jhalf * 16;

  // per-thread staging source pointers (row sr0 / sr0+32)
  const bf16* ksrc0 = kb + (size_t)(jhalf * 1024 + sr0) * INNER_ + scg;
  const bf16* ksrc1 = kb + (size_t)(jhalf * 1024 + sr0 + 32) * INNER_ + scg;
  const bf16* vsrc0 = vb + (size_t)sr0 * NB_ + jhalf * 1024 + scg;
  const bf16* vsrc1 = vb + (size_t)(sr0 + 32) * NB_ + jhalf * 1024 + scg;

  ushort8_t kr0, kr1, vr0, vr1;
  kr0 = *(const ushort8_t*)(ksrc0);
  kr1 = *(const ushort8_t*)(ksrc1);
  vr0 = *(const ushort8_t*)(vsrc0);
  vr1 = *(const ushort8_t*)(vsrc1);
  u64 smw = mrp[0] >> (quad * 4);

  for (int it = 0; it < 16; it++) {
    __syncthreads();  // previous tile's LDS reads complete
    *(ushort8_t*)(&Ks[sr0 * 72 + scg])        = kr0;
    *(ushort8_t*)(&Ks[(sr0 + 32) * 72 + scg]) = kr1;
    *(ushort8_t*)(&Vs[sr0 * 72 + scg])        = vr0;
    *(ushort8_t*)(&Vs[(sr0 + 32) * 72 + scg]) = vr1;
    __syncthreads();  // LDS tile ready

    u64 nsm = smw;
    if (it < 15) {
      int joff = (it + 1) * 64;
      kr0 = *(const ushort8_t*)(ksrc0 + (size_t)joff * INNER_);
      kr1 = *(const ushort8_t*)(ksrc1 + (size_t)joff * INNER_);
      vr0 = *(const ushort8_t*)(vsrc0 + joff);
      vr1 = *(const ushort8_t*)(vsrc1 + joff);
      nsm = mrp[it + 1] >> (quad * 4);
    }

    // St = K.Q^T : 4 j-subtiles of 16
    f32x4 st[4];
#pragma unroll
    for (int nt = 0; nt < 4; nt++) {
      bf16x8 a0 = *(const bf16x8*)(&Ks[(nt * 16 + lm) * 72 + q8]);
      bf16x8 a1 = *(const bf16x8*)(&Ks[(nt * 16 + lm) * 72 + 32 + q8]);
      f32x4 a = {0.f, 0.f, 0.f, 0.f};
      a = MFMA32(a0, bq0, a);
      a = MFMA32(a1, bq1, a);
      st[nt] = a;
    }

    // p = exp2(s*scale2), zero dead via bit
    float pr[4][4];
#pragma unroll
    for (int nt = 0; nt < 4; nt++)
#pragma unroll
      for (int r = 0; r < 4; r++) {
        float p = exp2f(st[nt][r] * scale2);
        unsigned live = (unsigned)(smw >> (nt * 16 + r)) & 1u;
        pr[nt][r] = live ? p : 0.0f;
      }

    float s0 = (pr[0][0] + pr[0][1]) + (pr[0][2] + pr[0][3]);
    float s1 = (pr[1][0] + pr[1][1]) + (pr[1][2] + pr[1][3]);
    float s2 = (pr[2][0] + pr[2][1]) + (pr[2][2] + pr[2][3]);
    float s3 = (pr[3][0] + pr[3][1]) + (pr[3][2] + pr[3][3]);
    psum += (s0 + s1) + (s2 + s3);

    // P store: row i = lm, j = nt*16 + quad*4 + r (b64 writes, same-wave)
#pragma unroll
    for (int nt = 0; nt < 4; nt++) {
      ushort4 pk;
      pk.x = bfbits(pr[nt][0]);
      pk.y = bfbits(pr[nt][1]);
      pk.z = bfbits(pr[nt][2]);
      pk.w = bfbits(pr[nt][3]);
      *(ushort4*)(Pw + lm * 72 + nt * 16 + quad * 4) = pk;
    }

    // PV: A = P [m=i][k=j], B = V^T [n=d][k=j] -> O[i][d]
    bf16x8 ap0 = *(const bf16x8*)(&Pw[lm * 72 + q8]);
    bf16x8 ap1 = *(const bf16x8*)(&Pw[lm * 72 + 32 + q8]);
#pragma unroll
    for (int c = 0; c < 4; c++) {
      bf16x8 v0 = *(const bf16x8*)(&Vs[(c * 16 + lm) * 72 + q8]);
      bf16x8 v1 = *(const bf16x8*)(&Vs[(c * 16 + lm) * 72 + 32 + q8]);
      oacc[c] = MFMA32(ap0, v0, oacc[c]);
      oacc[c] = MFMA32(ap1, v1, oacc[c]);
    }
    smw = nsm;
  }

  // row sums across quads (row i = lm)
  psum += __shfl_xor(psum, 16);
  psum += __shfl_xor(psum, 32);

  // -------- intra-block merge of the two j-halves --------
  __syncthreads();
  if (quad == 0) Lbuf[jhalf * 64 + w4 * 16 + lm] = psum;
  if (jhalf == 1) {
#pragma unroll
    for (int c = 0; c < 4; c++)
#pragma unroll
      for (int r = 0; r < 4; r++)
        Om[w4 * (16 * 66) + (quad * 4 + r) * 66 + c * 16 + lm] = oacc[c][r];
  }
  __syncthreads();
  if (jhalf == 0) {
    int mrow = i0 + w4 * 16 + quad * 4;
    float inv[4];
#pragma unroll
    for (int r = 0; r < 4; r++) {
      float l = Lbuf[w4 * 16 + quad * 4 + r] + Lbuf[64 + w4 * 16 + quad * 4 + r];
      inv[r] = 1.0f / l;
    }
#pragma unroll
    for (int c = 0; c < 4; c++) {
      int col = h * DH_ + c * 16 + lm;
#pragma unroll
      for (int r = 0; r < 4; r++) {
        float o = oacc[c][r] + Om[w4 * (16 * 66) + (quad * 4 + r) * 66 + c * 16 + lm];
        size_t idx = (size_t)(bidx * NA_ + mrow + r) * INNER_ + col;
        float gv = b2f(__builtin_bit_cast(unsigned short, g[idx]));
        float sig = 1.0f / (1.0f + __expf(-gv));
        float val = o * inv[r] * sig;
        unsigned short hb = bfbits(val);
        gh[idx] = __builtin_bit_cast(bf16, hb);
        gl[idx] = __float2bfloat16(val - b2f(hb));
      }
    }
  }
}

// ---------------- final GEMM in split-bf16 (hi/lo), 32x64 tiles, fp32 out -------
__global__ __launch_bounds__(256) void gemm_split_kernel(
    const bf16* __restrict__ Ah, const bf16* __restrict__ Al,
    const bf16* __restrict__ Bh, const bf16* __restrict__ Bl,
    const float* __restrict__ bias, float* __restrict__ C) {
  constexpr int K = 512, N = 256;
  __shared__ __align__(16) bf16 Ash[32 * 72];
  __shared__ __align__(16) bf16 Asl[32 * 72];
  __shared__ __align__(16) bf16 Bsh[64 * 72];
  __shared__ __align__(16) bf16 Bsl[64 * 72];
  int n0 = blockIdx.x * 64, m0 = blockIdx.y * 32;
  int t = threadIdx.x, wave = t >> 6, lane = t & 63;
  int lm = lane & 15, quad = lane >> 4, q8 = quad * 8;
  int wm = (wave & 1) * 16, wn = (wave >> 1) * 32;
  f32x4 acc[2] = {};
  for (int k0 = 0; k0 < K; k0 += 64) {
    __syncthreads();
    {
      int r = t >> 3, cg = t & 7;
      size_t ga = (size_t)(m0 + r) * K + k0 + cg * 8;
      *(ushort8_t*)(&Ash[r * 72 + cg * 8]) = *(const ushort8_t*)(Ah + ga);
      *(ushort8_t*)(&Asl[r * 72 + cg * 8]) = *(const ushort8_t*)(Al + ga);
    }
#pragma unroll
    for (int i = 0; i < 2; i++) {
      int id = t + 256 * i, r = id >> 3, cg = id & 7;
      size_t gb = (size_t)(n0 + r) * K + k0 + cg * 8;
      *(ushort8_t*)(&Bsh[r * 72 + cg * 8]) = *(const ushort8_t*)(Bh + gb);
      *(ushort8_t*)(&Bsl[r * 72 + cg * 8]) = *(const ushort8_t*)(Bl + gb);
    }
    __syncthreads();
#pragma unroll
    for (int kk = 0; kk < 64; kk += 32) {
      bf16x8 ah = *(const bf16x8*)(&Ash[(wm + lm) * 72 + kk + q8]);
      bf16x8 al = *(const bf16x8*)(&Asl[(wm + lm) * 72 + kk + q8]);
#pragma unroll
      for (int ni = 0; ni < 2; ni++) {
        bf16x8 bh_ = *(const bf16x8*)(&Bsh[(wn + ni * 16 + lm) * 72 + kk + q8]);
        bf16x8 bl_ = *(const bf16x8*)(&Bsl[(wn + ni * 16 + lm) * 72 + kk + q8]);
        acc[ni] = MFMA32(ah, bh_, acc[ni]);
        acc[ni] = MFMA32(ah, bl_, acc[ni]);
        acc[ni] = MFMA32(al, bh_, acc[ni]);
      }
    }
  }
#pragma unroll
  for (int ni = 0; ni < 2; ni++) {
    int n = n0 + wn + ni * 16 + lm;
    float bvv = bias[n];
    int mb = m0 + wm + quad * 4;
#pragma unroll
    for (int r = 0; r < 4; r++) C[(size_t)(mb + r) * N + n] = acc[ni][r] + bvv;
  }
}

extern "C" void kernel_launch(void* const* d_in, const int* in_sizes, int n_in,
                              void* d_out, int out_size, void* d_ws, size_t ws_size,
                              hipStream_t stream) {
  const float* feat_a = (const float*)d_in[0];
  const float* feat_b = (const float*)d_in[1];
  const void*  mask   = d_in[2];
  const float* Wq = (const float*)d_in[3];
  const float* bq = (const float*)d_in[4];
  const float* Wk = (const float*)d_in[5];
  const float* bk = (const float*)d_in[6];
  const float* Wv = (const float*)d_in[7];
  const float* bv = (const float*)d_in[8];
  const float* Wg = (const float*)d_in[9];
  const float* bg = (const float*)d_in[10];
  const float* Wo = (const float*)d_in[11];
  const float* bo = (const float*)d_in[12];
  const float* law = (const float*)d_in[13];
  const float* lab = (const float*)d_in[14];
  const float* lbw = (const float*)d_in[15];
  const float* lbb = (const float*)d_in[16];
  const float* qlw = (const float*)d_in[17];
  const float* qlb = (const float*)d_in[18];
  const float* klw = (const float*)d_in[19];
  const float* klb = (const float*)d_in[20];

  char* ws = (char*)d_ws;
  size_t off = 0;
  auto alloc = [&](size_t bytes) -> void* {
    void* p = ws + off;
    off += (bytes + 255) & ~(size_t)255;
    return p;
  };
  bf16* fa    = (bf16*)alloc((size_t)MROWS * 256 * 2);
  bf16* fb    = (bf16*)alloc((size_t)MROWS * 256 * 2);
  bf16* Wqt   = (bf16*)alloc((size_t)131072 * 2);
  bf16* Wkt   = (bf16*)alloc((size_t)131072 * 2);
  bf16* Wvt   = (bf16*)alloc((size_t)131072 * 2);
  bf16* Wgt   = (bf16*)alloc((size_t)131072 * 2);
  bf16* Woth  = (bf16*)alloc((size_t)131072 * 2);
  bf16* Wotl  = (bf16*)alloc((size_t)131072 * 2);
  bf16* qb_   = (bf16*)alloc((size_t)MROWS * 512 * 2);
  bf16* kb_   = (bf16*)alloc((size_t)MROWS * 512 * 2);
  bf16* vtb   = (bf16*)alloc((size_t)1024 * 2048 * 2);
  bf16* gbuf  = (bf16*)alloc((size_t)MROWS * 512 * 2);
  bf16* gh    = (bf16*)alloc((size_t)MROWS * 512 * 2);
  bf16* gl    = (bf16*)alloc((size_t)MROWS * 512 * 2);
  u64*  mbits = (u64*)alloc((size_t)131072 * 8);

  prep_kernel<<<6656, 256, 0, stream>>>(
      feat_a, feat_b, law, lab, lbw, lbb, fa, fb,
      Wq, Wk, Wv, Wg, Wo, Wqt, Wkt, Wvt, Wgt, Woth, Wotl, mask, mbits);
  gemm4_kernel<<<dim3(256, 1, 4), 256, 0, stream>>>(
      fa, fb, Wqt, Wkt, Wgt, Wvt, bq, bk, bg, bv,
      qlw, qlb, klw, klb, qb_, kb_, gbuf, vtb);
  attn_kernel<<<dim3(32, 16), 512, 0, stream>>>(qb_, kb_, vtb, gbuf, mbits, gh, gl);
  gemm_split_kernel<<<dim3(4, 128), 256, 0, stream>>>(gh, gl, Woth, Wotl, bo, (float*)d_out);
}